// Round 1
// 1090.784 us; speedup vs baseline: 1.0924x; 1.0924x over previous
//
#include <hip/hip_runtime.h>
#include <hip/hip_bf16.h>
#include <math.h>

// MoE MLP: B=4, S=2048, H=1024, D_FF=4096, E=8, top-2.
// Round 3: remove FC2 atomic epilogue (plain bf16 Y store + combine kernel via
// inverse position map), fast sigmoid-form gelu in FC1 epilogue (replaces erff),
// drop out-memset, merge init+setup launches. GEMM main loop stays the verified
// m97 structure (128x128 tile, BK=32, global_load_lds w=16, ds_read_b128,
// 16x16x32_bf16 MFMA).

#define TT  8192    // tokens = B*S
#define HD  1024    // hidden
#define DFF 4096    // ffn dim
#define NE  8       // experts
#define ROWCAP 17408   // 16384 gathered rows + per-expert pad to 128 (<= 17400)
#define MAXTILES 136   // sum ceil(counts[e]/128) <= 135

typedef __attribute__((ext_vector_type(8))) short short8;
typedef __attribute__((ext_vector_type(4))) float f32x4;

// fp32 -> bf16 round-to-nearest-even (finite inputs)
static __device__ __forceinline__ unsigned short f2bf(float f) {
    unsigned int u = __float_as_uint(f);
    unsigned int r = (u + 0x7fffu + ((u >> 16) & 1u)) >> 16;
    return (unsigned short)r;
}

static __device__ __forceinline__ float bf2f(unsigned short u) {
    return __uint_as_float((unsigned int)u << 16);
}

// gelu tanh-form via sigmoid: v * sigmoid(1.5957691*(v + 0.044715 v^3)).
// Max abs deviation from exact erf-gelu ~3e-4, far below bf16 storage rounding.
// Large |v| safe: exp overflow -> v/inf -> 0 (neg side), exp->0 -> v (pos side).
static __device__ __forceinline__ float gelu_fast(float v) {
    const float s = v * (1.5957691f + 0.07135481f * v * v);
    return v / (1.f + __expf(-s));
}

// async global->LDS, 16 bytes per lane. LDS dest = wave-uniform base + lane*16.
static __device__ __forceinline__ void gload_lds16(const void* gp, void* lp) {
    __builtin_amdgcn_global_load_lds(
        (__attribute__((address_space(1))) void*)(void*)gp,
        (__attribute__((address_space(3))) void*)lp,
        16, 0, 0);
}

// ------------------------------------------------------------- weights -> bf16
__global__ __launch_bounds__(256) void cvt_w_kernel(const float* __restrict__ s,
                                                    unsigned short* __restrict__ d) {
    const long i = (long)blockIdx.x * 256 + threadIdx.x;
    float4 v = ((const float4*)s)[i];
    ushort4 o;
    o.x = f2bf(v.x); o.y = f2bf(v.y); o.z = f2bf(v.z); o.w = f2bf(v.w);
    ((ushort4*)d)[i] = o;
}

// ------------------------------------------------------------- router
// One wave per token; fp64 logits so top-k selection matches numpy ordering
// on near-ties (verified passing in earlier rounds).
__global__ __launch_bounds__(256) void router_kernel(const float* __restrict__ x,
                                                     const float* __restrict__ wr,
                                                     int* __restrict__ tokE,
                                                     float* __restrict__ tokW,
                                                     int* __restrict__ counts) {
    const int token = blockIdx.x * 4 + (threadIdx.x >> 6);
    const int lane = threadIdx.x & 63;
    const float* xp = x + (long)token * HD;
    double lg[NE];
#pragma unroll
    for (int e = 0; e < NE; ++e) {
        const float* wp = wr + e * HD;
        double s = 0.0;
        for (int i = lane; i < HD; i += 64) s += (double)xp[i] * (double)wp[i];
#pragma unroll
        for (int off = 32; off > 0; off >>= 1) s += __shfl_xor(s, off, 64);
        lg[e] = s;
    }
    if (lane == 0) {
        int i0 = 0; double v0 = lg[0];
#pragma unroll
        for (int e = 1; e < NE; ++e) if (lg[e] > v0) { v0 = lg[e]; i0 = e; }
        int i1 = -1; double v1 = -1e300;
#pragma unroll
        for (int e = 0; e < NE; ++e) if (e != i0 && lg[e] > v1) { v1 = lg[e]; i1 = e; }
        double p = exp(v1 - v0);  // v1 <= v0
        double d = 1.0 + p;
        tokE[token * 2] = i0;     tokW[token * 2] = (float)(1.0 / d);
        tokE[token * 2 + 1] = i1; tokW[token * 2 + 1] = (float)(p / d);
        atomicAdd(&counts[i0], 1);
        atomicAdd(&counts[i1], 1);
    }
}

// ------------------------------------------------------------- init + tile map
// Blocks 0..ROWCAP/256-1: default pad rows (token 0; cw handled by combine --
// pad rows are simply never read back). Last block, thread 0: single-thread
// scan over 8 experts -> per-expert row offsets (padded to 128) + tile map.
__global__ __launch_bounds__(256) void init_setup_kernel(const int* __restrict__ counts,
                                                         int* __restrict__ cursor,
                                                         int* __restrict__ tileExpert,
                                                         int* __restrict__ tileRow0,
                                                         int* __restrict__ rowTok) {
    const int i = blockIdx.x * 256 + threadIdx.x;
    if (i < ROWCAP) rowTok[i] = 0;
    if (blockIdx.x == gridDim.x - 1 && threadIdx.x == 0) {
        int off = 0, t = 0;
        for (int e = 0; e < NE; ++e) {
            cursor[e] = off;
            const int padded = (counts[e] + 127) & ~127;
            for (int j = 0; j < padded / 128; ++j) {
                tileExpert[t] = e;
                tileRow0[t] = off + j * 128;
                ++t;
            }
            off += padded;
        }
        for (; t < MAXTILES; ++t) tileExpert[t] = -1;
    }
}

// scatter: fill row->token map AND the inverse map token->row position
__global__ __launch_bounds__(256) void scatter_kernel(const int* __restrict__ tokE,
                                                      int* __restrict__ cursor,
                                                      int* __restrict__ rowTok,
                                                      int* __restrict__ posOf) {
    const int t = blockIdx.x * 256 + threadIdx.x;
#pragma unroll
    for (int j = 0; j < 2; ++j) {
        const int e = tokE[t * 2 + j];
        const int pos = atomicAdd(&cursor[e], 1);
        rowTok[pos] = t;
        posOf[t * 2 + j] = pos;
    }
}

// gather + cvt: Xg[row][:] = bf16(x[rowTok[row]][:])
__global__ __launch_bounds__(256) void gather_kernel(const float* __restrict__ x,
                                                     const int* __restrict__ rowTok,
                                                     unsigned short* __restrict__ Xg) {
    const int row = blockIdx.x;
    const int tok = rowTok[row];
    const float4 v = ((const float4*)(x + (long)tok * HD))[threadIdx.x];
    ushort4 o;
    o.x = f2bf(v.x); o.y = f2bf(v.y); o.z = f2bf(v.z); o.w = f2bf(v.w);
    ((ushort4*)(Xg + (long)row * HD))[threadIdx.x] = o;
}

// ------------------------------------------------------------- grouped GEMM
// C[m,n] = sum_k A[row0+m,k] * W[e][n0+n,k], both bf16, m97 structure.
// EPI=0: Hout[row, col] = bf16(gelu(C + bias))
// EPI=1: Hout[row, col] = bf16(C + bias)          (combine kernel applies cw)
template <int EPI, int N, int K>
__global__ __launch_bounds__(256) void gemm_moe(
    const unsigned short* __restrict__ A,
    const unsigned short* __restrict__ W,
    const int* __restrict__ tileExpert,
    const int* __restrict__ tileRow0,
    unsigned short* __restrict__ Hout,
    const float* __restrict__ bias) {
    const int e = tileExpert[blockIdx.x];
    if (e < 0) return;

    __shared__ unsigned short As[128 * 32];  // 8 KB [m][k]
    __shared__ unsigned short Bs[128 * 32];  // 8 KB [n][k]

    const int tid = threadIdx.x;
    const int lane = tid & 63;
    const int quad = lane >> 4;
    const int l15 = lane & 15;
    const int wy = (tid >> 6) >> 1;
    const int wx = (tid >> 6) & 1;
    const long row0 = tileRow0[blockIdx.x];
    const long n0 = (long)blockIdx.y * 128;
    const unsigned short* Ab = A + row0 * K;
    const unsigned short* Bb = W + ((long)e * N + n0) * K;

    f32x4 acc[4][4];
#pragma unroll
    for (int i = 0; i < 4; ++i)
#pragma unroll
        for (int j = 0; j < 4; ++j) acc[i][j] = (f32x4){0.f, 0.f, 0.f, 0.f};

    for (int k0 = 0; k0 < K; k0 += 32) {
        // each tile: 128x32 bf16 = 8 KB = 512 x 16B chunks -> 2 per thread.
        // chunk c: row = c>>2, k-off = (c&3)*8; LDS dest = c*16B (contiguous
        // per wave -> satisfies the uniform-base + lane*16 rule).
#pragma unroll
        for (int it = 0; it < 2; ++it) {
            const int c = it * 256 + tid;
            gload_lds16(Ab + (long)(c >> 2) * K + k0 + (c & 3) * 8, As + c * 8);
            gload_lds16(Bb + (long)(c >> 2) * K + k0 + (c & 3) * 8, Bs + c * 8);
        }
        __syncthreads();

        // A/B fragments: [m = l15][k = quad*8 + j]
        short8 af[4];
#pragma unroll
        for (int mi = 0; mi < 4; ++mi)
            af[mi] = *(const short8*)(As + (wy * 64 + mi * 16 + l15) * 32 + quad * 8);
#pragma unroll
        for (int ni = 0; ni < 4; ++ni) {
            const short8 bf = *(const short8*)(Bs + (wx * 64 + ni * 16 + l15) * 32 + quad * 8);
#pragma unroll
            for (int mi = 0; mi < 4; ++mi)
                acc[mi][ni] = __builtin_amdgcn_mfma_f32_16x16x32_bf16(
                    af[mi], bf, acc[mi][ni], 0, 0, 0);
        }
        __syncthreads();
    }

    // epilogue: C/D layout row = quad*4 + r, col = l15 (verified m89/m91)
#pragma unroll
    for (int mi = 0; mi < 4; ++mi) {
        const int lrow0 = wy * 64 + mi * 16 + quad * 4;
#pragma unroll
        for (int ni = 0; ni < 4; ++ni) {
            const long col = n0 + wx * 64 + ni * 16 + l15;
            const float bcol = bias[(long)e * N + col];
#pragma unroll
            for (int r = 0; r < 4; ++r) {
                const long grow = row0 + lrow0 + r;
                float v = acc[mi][ni][r] + bcol;
                if constexpr (EPI == 0) v = gelu_fast(v);
                Hout[grow * N + col] = f2bf(v);
            }
        }
    }
}

// ------------------------------------------------------------- combine
// out[t][:] = w0 * Y[pos0][:] + w1 * Y[pos1][:]   (Y bf16, accumulate fp32)
__global__ __launch_bounds__(256) void combine_kernel(const unsigned short* __restrict__ Y,
                                                      const int* __restrict__ posOf,
                                                      const float* __restrict__ tokW,
                                                      float* __restrict__ out) {
    const int t = blockIdx.x;
    const int p0 = posOf[t * 2];
    const int p1 = posOf[t * 2 + 1];
    const float w0 = tokW[t * 2];
    const float w1 = tokW[t * 2 + 1];
    const ushort4 a = ((const ushort4*)(Y + (long)p0 * HD))[threadIdx.x];
    const ushort4 b = ((const ushort4*)(Y + (long)p1 * HD))[threadIdx.x];
    float4 o;
    o.x = w0 * bf2f(a.x) + w1 * bf2f(b.x);
    o.y = w0 * bf2f(a.y) + w1 * bf2f(b.y);
    o.z = w0 * bf2f(a.z) + w1 * bf2f(b.z);
    o.w = w0 * bf2f(a.w) + w1 * bf2f(b.w);
    ((float4*)(out + (long)t * HD))[threadIdx.x] = o;
}

// ------------------------------------------------------------- launch
extern "C" void kernel_launch(void* const* d_in, const int* in_sizes, int n_in,
                              void* d_out, int out_size, void* d_ws, size_t ws_size,
                              hipStream_t stream) {
    const float* x  = (const float*)d_in[0];   // [4,2048,1024]
    const float* wr = (const float*)d_in[1];   // [8,1024]
    const float* w1 = (const float*)d_in[2];   // [8,4096,1024]
    const float* b1 = (const float*)d_in[3];   // [8,4096]
    const float* w2 = (const float*)d_in[4];   // [8,1024,4096]
    const float* b2 = (const float*)d_in[5];   // [8,1024]
    float* out = (float*)d_out;                // [4,2048,1024] fp32

    // workspace layout (~246 MB)
    char* p = (char*)d_ws;
    auto alloc = [&](size_t bytes) {
        char* r = p;
        p += (bytes + 255) & ~(size_t)255;
        return r;
    };
    unsigned short* Xg  = (unsigned short*)alloc((size_t)ROWCAP * HD * 2);   // 35.7 MB
    unsigned short* H1g = (unsigned short*)alloc((size_t)ROWCAP * DFF * 2);  // 142.6 MB
    unsigned short* Wb  = (unsigned short*)alloc((size_t)NE * DFF * HD * 2); // 67.1 MB (reused w1/w2)
    int*   rowTok  = (int*)alloc((size_t)ROWCAP * 4);
    int*   posOf   = (int*)alloc((size_t)TT * 2 * 4);
    int*   tokE    = (int*)alloc((size_t)TT * 2 * 4);
    float* tokW    = (float*)alloc((size_t)TT * 2 * 4);
    int*   counts  = (int*)alloc(64);
    int*   cursor  = (int*)alloc(64);
    int*   tileExpert = (int*)alloc(MAXTILES * 4);
    int*   tileRow0   = (int*)alloc(MAXTILES * 4);

    // Yg (FC2 per-row output, bf16) reuses the Xg slot: Xg is dead after FC1,
    // and FC2 starts only after FC1 completes (stream order). Same size.
    unsigned short* Yg = Xg;

    hipMemsetAsync(counts, 0, 64, stream);

    router_kernel<<<dim3(TT / 4), dim3(256), 0, stream>>>(x, wr, tokE, tokW, counts);
    init_setup_kernel<<<dim3(ROWCAP / 256 + 1), dim3(256), 0, stream>>>(
        counts, cursor, tileExpert, tileRow0, rowTok);
    scatter_kernel<<<dim3(TT / 256), dim3(256), 0, stream>>>(tokE, cursor, rowTok, posOf);
    gather_kernel<<<dim3(ROWCAP), dim3(256), 0, stream>>>(x, rowTok, Xg);

    // FC1: H1g = gelu(Xg @ w1[e]^T + b1[e]) over gathered rows
    cvt_w_kernel<<<dim3(NE * DFF * HD / 4 / 256), dim3(256), 0, stream>>>(w1, Wb);
    gemm_moe<0, DFF, HD><<<dim3(MAXTILES, DFF / 128), dim3(256), 0, stream>>>(
        Xg, Wb, tileExpert, tileRow0, H1g, b1);

    // FC2: Yg[row] = H1g[row] @ w2[e]^T + b2[e]  (plain bf16 stores, no atomics)
    cvt_w_kernel<<<dim3(NE * HD * DFF / 4 / 256), dim3(256), 0, stream>>>(w2, Wb);
    gemm_moe<1, HD, DFF><<<dim3(MAXTILES, HD / 128), dim3(256), 0, stream>>>(
        H1g, Wb, tileExpert, tileRow0, Yg, b2);

    // combine: out[t] = w0 * Yg[pos0(t)] + w1 * Yg[pos1(t)]
    combine_kernel<<<dim3(TT), dim3(256), 0, stream>>>(Yg, posOf, tokW, out);
}

// Round 2
// 1078.440 us; speedup vs baseline: 1.1049x; 1.0114x over previous
//
#include <hip/hip_runtime.h>
#include <hip/hip_bf16.h>
#include <math.h>

// MoE MLP: B=4, S=2048, H=1024, D_FF=4096, E=8, top-2.
// Round 4: port grouped GEMM to the 256-tile 8-phase schedule (T2 LDS
// XOR-swizzle + T3 phase split + T4 counted vmcnt across raw s_barrier +
// T5 setprio). FC1: BM=256xBN=256, waves 2x4. FC2: BM=256xBN=128, waves 4x2
// (grid 576 blocks -> better pass granularity at N=1024).
// Also: ws_size-gated bf16 weight caching via magic flag (safe under
// workspace re-poisoning: poison kills magic -> reconvert).

#define TT  8192    // tokens = B*S
#define HD  1024    // hidden
#define DFF 4096    // ffn dim
#define NE  8       // experts
#define ROWCAP 18432   // 16384 gathered rows + per-expert pad to 256 (<= 18424)
#define MAXTILES 72    // sum ceil(counts[e]/256) <= 64 + 8

#define MAGIC0 0x9e3779b97f4a7c15ULL
#define MAGIC1 0xc2b2ae3d27d4eb4fULL

typedef __attribute__((ext_vector_type(8))) short short8;
typedef __attribute__((ext_vector_type(4))) float f32x4;

// fp32 -> bf16 round-to-nearest-even (finite inputs)
static __device__ __forceinline__ unsigned short f2bf(float f) {
    unsigned int u = __float_as_uint(f);
    unsigned int r = (u + 0x7fffu + ((u >> 16) & 1u)) >> 16;
    return (unsigned short)r;
}

static __device__ __forceinline__ float bf2f(unsigned short u) {
    return __uint_as_float((unsigned int)u << 16);
}

// gelu tanh-form via sigmoid: v * sigmoid(1.5957691*(v + 0.044715 v^3)).
static __device__ __forceinline__ float gelu_fast(float v) {
    const float s = v * (1.5957691f + 0.07135481f * v * v);
    return v / (1.f + __expf(-s));
}

// async global->LDS, 16 bytes per lane. LDS dest = wave-uniform base + lane*16.
static __device__ __forceinline__ void gload_lds16(const void* gp, void* lp) {
    __builtin_amdgcn_global_load_lds(
        (__attribute__((address_space(1))) void*)(void*)gp,
        (__attribute__((address_space(3))) void*)lp,
        16, 0, 0);
}

// ------------------------------------------------------------- weights -> bf16
// Grid-stride; if flag holds the magic, converted weights are already cached
// in workspace from a previous launch -> early-exit (cheap: 2048 blocks).
__global__ __launch_bounds__(256) void cvt_w_kernel(const float* __restrict__ s,
                                                    unsigned short* __restrict__ d,
                                                    long n4,
                                                    const unsigned long long* __restrict__ flag) {
    if (flag && flag[0] == MAGIC0 && flag[1] == MAGIC1) return;
    for (long i = (long)blockIdx.x * 256 + threadIdx.x; i < n4;
         i += (long)gridDim.x * 256) {
        float4 v = ((const float4*)s)[i];
        ushort4 o;
        o.x = f2bf(v.x); o.y = f2bf(v.y); o.z = f2bf(v.z); o.w = f2bf(v.w);
        ((ushort4*)d)[i] = o;
    }
}

__global__ void set_flag_kernel(unsigned long long* __restrict__ flag) {
    if (threadIdx.x == 0 && blockIdx.x == 0) {
        flag[0] = MAGIC0;
        flag[1] = MAGIC1;
    }
}

// ------------------------------------------------------------- router
// One wave per token; fp64 logits so top-k selection matches numpy ordering
// on near-ties (verified passing in earlier rounds).
__global__ __launch_bounds__(256) void router_kernel(const float* __restrict__ x,
                                                     const float* __restrict__ wr,
                                                     int* __restrict__ tokE,
                                                     float* __restrict__ tokW,
                                                     int* __restrict__ counts) {
    const int token = blockIdx.x * 4 + (threadIdx.x >> 6);
    const int lane = threadIdx.x & 63;
    const float* xp = x + (long)token * HD;
    double lg[NE];
#pragma unroll
    for (int e = 0; e < NE; ++e) {
        const float* wp = wr + e * HD;
        double s = 0.0;
        for (int i = lane; i < HD; i += 64) s += (double)xp[i] * (double)wp[i];
#pragma unroll
        for (int off = 32; off > 0; off >>= 1) s += __shfl_xor(s, off, 64);
        lg[e] = s;
    }
    if (lane == 0) {
        int i0 = 0; double v0 = lg[0];
#pragma unroll
        for (int e = 1; e < NE; ++e) if (lg[e] > v0) { v0 = lg[e]; i0 = e; }
        int i1 = -1; double v1 = -1e300;
#pragma unroll
        for (int e = 0; e < NE; ++e) if (e != i0 && lg[e] > v1) { v1 = lg[e]; i1 = e; }
        double p = exp(v1 - v0);  // v1 <= v0
        double d = 1.0 + p;
        tokE[token * 2] = i0;     tokW[token * 2] = (float)(1.0 / d);
        tokE[token * 2 + 1] = i1; tokW[token * 2 + 1] = (float)(p / d);
        atomicAdd(&counts[i0], 1);
        atomicAdd(&counts[i1], 1);
    }
}

// ------------------------------------------------------------- init + tile map
__global__ __launch_bounds__(256) void init_setup_kernel(const int* __restrict__ counts,
                                                         int* __restrict__ cursor,
                                                         int* __restrict__ tileExpert,
                                                         int* __restrict__ tileRow0,
                                                         int* __restrict__ rowTok) {
    const int i = blockIdx.x * 256 + threadIdx.x;
    if (i < ROWCAP) rowTok[i] = 0;
    if (blockIdx.x == gridDim.x - 1 && threadIdx.x == 0) {
        int off = 0, t = 0;
        for (int e = 0; e < NE; ++e) {
            cursor[e] = off;
            const int padded = (counts[e] + 255) & ~255;
            for (int j = 0; j < padded / 256; ++j) {
                tileExpert[t] = e;
                tileRow0[t] = off + j * 256;
                ++t;
            }
            off += padded;
        }
        for (; t < MAXTILES; ++t) tileExpert[t] = -1;
    }
}

// scatter: fill row->token map AND the inverse map token->row position
__global__ __launch_bounds__(256) void scatter_kernel(const int* __restrict__ tokE,
                                                      int* __restrict__ cursor,
                                                      int* __restrict__ rowTok,
                                                      int* __restrict__ posOf) {
    const int t = blockIdx.x * 256 + threadIdx.x;
#pragma unroll
    for (int j = 0; j < 2; ++j) {
        const int e = tokE[t * 2 + j];
        const int pos = atomicAdd(&cursor[e], 1);
        rowTok[pos] = t;
        posOf[t * 2 + j] = pos;
    }
}

// gather + cvt: Xg[row][:] = bf16(x[rowTok[row]][:])
__global__ __launch_bounds__(256) void gather_kernel(const float* __restrict__ x,
                                                     const int* __restrict__ rowTok,
                                                     unsigned short* __restrict__ Xg) {
    const int row = blockIdx.x;
    const int tok = rowTok[row];
    const float4 v = ((const float4*)(x + (long)tok * HD))[threadIdx.x];
    ushort4 o;
    o.x = f2bf(v.x); o.y = f2bf(v.y); o.z = f2bf(v.z); o.w = f2bf(v.w);
    ((ushort4*)(Xg + (long)row * HD))[threadIdx.x] = o;
}

// ------------------------------------------------------------- grouped GEMM
// 256-row tile, BK=64, 8 waves (WM x WN), double-buffered LDS, 4 quadrant
// phases per K-tile with counted vmcnt across raw s_barrier (T3+T4),
// XOR-swizzled LDS (T2: stage linear dest + inverse-swizzled global source,
// read with matching XOR -> 2-way conflicts = free), setprio on MFMA (T5).
// C[m,n] = sum_k A[row0+m,k] * W[e][n0+n,k] (both bf16).
// EPI=0: Hout = bf16(gelu(C + bias));  EPI=1: Hout = bf16(C + bias).
template <int EPI, int N, int K, int BN, int WM, int WN>
__global__ __launch_bounds__(512, 2) void gemm8(
    const unsigned short* __restrict__ A,
    const unsigned short* __restrict__ W,
    const int* __restrict__ tileExpert,
    const int* __restrict__ tileRow0,
    unsigned short* __restrict__ Hout,
    const float* __restrict__ bias) {
    constexpr int BM = 256, BK = 64;
    constexpr int NT = K / BK;
    constexpr int MREP = BM / WM / 16;   // fragment rows per wave
    constexpr int NREP = BN / WN / 16;   // fragment cols per wave
    constexpr int MIQ = MREP / 4;        // mi per quadrant phase
    constexpr int ACH = BM * BK / (512 * 8);  // A 16B-chunks per thread
    constexpr int BCH = BN * BK / (512 * 8);  // B 16B-chunks per thread
    constexpr int HALF = (BM + BN) * BK;      // ushort elements per buffer

    const int e = tileExpert[blockIdx.x];
    if (e < 0) return;

    __shared__ unsigned short smem[2 * HALF];  // FC1: 128 KB, FC2: 96 KB

    const int tid = threadIdx.x;
    const int lane = tid & 63;
    const int quad = lane >> 4;
    const int l15 = lane & 15;
    const int wid = tid >> 6;
    const int wr = wid / WN;
    const int wc = wid % WN;
    const int axor = (l15 & 7) << 4;   // row&7 == l15&7 for all fragment rows

    const long row0 = tileRow0[blockIdx.x];
    const long n0 = (long)blockIdx.y * BN;
    const unsigned short* Ab = A + row0 * K;
    const unsigned short* Bb = W + ((long)e * N + n0) * K;

    // per-thread staging sources: chunk c -> row=c>>3, slot=c&7; global source
    // pre-swizzled (slot ^ (row&7)) so linear LDS + XOR read are consistent.
    const unsigned short* aS[ACH];
    const unsigned short* bS[BCH];
    int aD[ACH], bD[BCH];
#pragma unroll
    for (int i = 0; i < ACH; ++i) {
        const int c = i * 512 + tid, r = c >> 3, s = c & 7;
        aS[i] = Ab + (long)r * K + (s ^ (r & 7)) * 8;
        aD[i] = c * 8;
    }
#pragma unroll
    for (int i = 0; i < BCH; ++i) {
        const int c = i * 512 + tid, r = c >> 3, s = c & 7;
        bS[i] = Bb + (long)r * K + (s ^ (r & 7)) * 8;
        bD[i] = c * 8;
    }

    f32x4 acc[MREP][NREP];
#pragma unroll
    for (int i = 0; i < MREP; ++i)
#pragma unroll
        for (int j = 0; j < NREP; ++j) acc[i][j] = (f32x4){0.f, 0.f, 0.f, 0.f};

    auto STAGE = [&](int buf, int t) {
        unsigned short* dst = smem + buf * HALF;
#pragma unroll
        for (int i = 0; i < ACH; ++i)
            gload_lds16(aS[i] + (long)t * BK, dst + aD[i]);
        unsigned short* dstB = dst + BM * BK;
#pragma unroll
        for (int i = 0; i < BCH; ++i)
            gload_lds16(bS[i] + (long)t * BK, dstB + bD[i]);
    };

    STAGE(0, 0);
#pragma unroll 1
    for (int t = 0; t < NT; ++t) {
        const int cur = t & 1;
        if (t + 1 < NT) {
            STAGE(cur ^ 1, t + 1);
            // own tile-t loads complete; next tile's ACH+BCH stay in flight.
            asm volatile("s_waitcnt vmcnt(%0)" ::"n"(ACH + BCH) : "memory");
        } else {
            asm volatile("s_waitcnt vmcnt(0)" ::: "memory");
        }
        __builtin_amdgcn_s_barrier();   // all waves' tile-t loads landed
        asm volatile("" ::: "memory");

        const unsigned short* Abuf = smem + cur * HALF;
        const unsigned short* Bbuf = Abuf + BM * BK;
        short8 bfr[NREP][2];
#pragma unroll
        for (int q = 0; q < 4; ++q) {
            if (q == 0) {
#pragma unroll
                for (int ni = 0; ni < NREP; ++ni)
#pragma unroll
                    for (int ks = 0; ks < 2; ++ks) {
                        const int rowb = wc * (BN / WN) + ni * 16 + l15;
                        bfr[ni][ks] = *(const short8*)((const char*)Bbuf +
                            ((rowb * (BK * 2) + ks * 64 + quad * 16) ^ axor));
                    }
            }
            short8 afr[MIQ][2];
#pragma unroll
            for (int i = 0; i < MIQ; ++i)
#pragma unroll
                for (int ks = 0; ks < 2; ++ks) {
                    const int rowa = wr * (BM / WM) + (q * MIQ + i) * 16 + l15;
                    afr[i][ks] = *(const short8*)((const char*)Abuf +
                        ((rowa * (BK * 2) + ks * 64 + quad * 16) ^ axor));
                }
            __builtin_amdgcn_s_setprio(1);
#pragma unroll
            for (int i = 0; i < MIQ; ++i)
#pragma unroll
                for (int ni = 0; ni < NREP; ++ni)
#pragma unroll
                    for (int ks = 0; ks < 2; ++ks)
                        acc[q * MIQ + i][ni] = __builtin_amdgcn_mfma_f32_16x16x32_bf16(
                            afr[i][ks], bfr[ni][ks], acc[q * MIQ + i][ni], 0, 0, 0);
            __builtin_amdgcn_s_setprio(0);
            __builtin_amdgcn_s_barrier();   // phase stagger (role-split)
            asm volatile("" ::: "memory");
        }
    }

    // epilogue: C/D layout row = quad*4 + r, col = l15 (verified m89/m91)
#pragma unroll
    for (int mi = 0; mi < MREP; ++mi) {
        const long grow0 = row0 + wr * (BM / WM) + mi * 16 + quad * 4;
#pragma unroll
        for (int ni = 0; ni < NREP; ++ni) {
            const long col = n0 + wc * (BN / WN) + ni * 16 + l15;
            const float bcol = bias[(long)e * N + col];
#pragma unroll
            for (int r = 0; r < 4; ++r) {
                float v = acc[mi][ni][r] + bcol;
                if constexpr (EPI == 0) v = gelu_fast(v);
                Hout[(grow0 + r) * N + col] = f2bf(v);
            }
        }
    }
}

// ------------------------------------------------------------- combine
// out[t][:] = w0 * Y[pos0][:] + w1 * Y[pos1][:]   (Y bf16, accumulate fp32)
__global__ __launch_bounds__(256) void combine_kernel(const unsigned short* __restrict__ Y,
                                                      const int* __restrict__ posOf,
                                                      const float* __restrict__ tokW,
                                                      float* __restrict__ out) {
    const int t = blockIdx.x;
    const int p0 = posOf[t * 2];
    const int p1 = posOf[t * 2 + 1];
    const float w0 = tokW[t * 2];
    const float w1 = tokW[t * 2 + 1];
    const ushort4 a = ((const ushort4*)(Y + (long)p0 * HD))[threadIdx.x];
    const ushort4 b = ((const ushort4*)(Y + (long)p1 * HD))[threadIdx.x];
    float4 o;
    o.x = w0 * bf2f(a.x) + w1 * bf2f(b.x);
    o.y = w0 * bf2f(a.y) + w1 * bf2f(b.y);
    o.z = w0 * bf2f(a.z) + w1 * bf2f(b.z);
    o.w = w0 * bf2f(a.w) + w1 * bf2f(b.w);
    ((float4*)(out + (long)t * HD))[threadIdx.x] = o;
}

// ------------------------------------------------------------- launch
extern "C" void kernel_launch(void* const* d_in, const int* in_sizes, int n_in,
                              void* d_out, int out_size, void* d_ws, size_t ws_size,
                              hipStream_t stream) {
    const float* x  = (const float*)d_in[0];   // [4,2048,1024]
    const float* wr = (const float*)d_in[1];   // [8,1024]
    const float* w1 = (const float*)d_in[2];   // [8,4096,1024]
    const float* b1 = (const float*)d_in[3];   // [8,4096]
    const float* w2 = (const float*)d_in[4];   // [8,1024,4096]
    const float* b2 = (const float*)d_in[5];   // [8,1024]
    float* out = (float*)d_out;                // [4,2048,1024] fp32

    const size_t WBYTES = (size_t)NE * DFF * HD * 2;  // 67.1 MB per weight
    // cached layout needs ~324 MB; fallback (shared Wb) needs ~257 MB.
    const bool cached = ws_size >= (size_t)(340u * 1024u * 1024u);

    char* p = (char*)d_ws;
    auto alloc = [&](size_t bytes) {
        char* r = p;
        p += (bytes + 255) & ~(size_t)255;
        return r;
    };
    unsigned short* Xg  = (unsigned short*)alloc((size_t)ROWCAP * HD * 2);   // 37.7 MB
    unsigned short* H1g = (unsigned short*)alloc((size_t)ROWCAP * DFF * 2);  // 151 MB
    unsigned short* Wb1 = (unsigned short*)alloc(WBYTES);                    // 67.1 MB
    unsigned short* Wb2 = cached ? (unsigned short*)alloc(WBYTES) : Wb1;
    int*   rowTok  = (int*)alloc((size_t)ROWCAP * 4);
    int*   posOf   = (int*)alloc((size_t)TT * 2 * 4);
    int*   tokE    = (int*)alloc((size_t)TT * 2 * 4);
    float* tokW    = (float*)alloc((size_t)TT * 2 * 4);
    int*   counts  = (int*)alloc(64);
    int*   cursor  = (int*)alloc(64);
    int*   tileExpert = (int*)alloc(MAXTILES * 4);
    int*   tileRow0   = (int*)alloc(MAXTILES * 4);
    unsigned long long* flag = (unsigned long long*)alloc(64);

    // Yg (FC2 per-row bf16 output) reuses the Xg slot (Xg dead after FC1).
    unsigned short* Yg = Xg;

    hipMemsetAsync(counts, 0, 64, stream);

    // weight conversion first (cached across launches when flag survives)
    const long n4w = (long)NE * DFF * HD / 4;
    cvt_w_kernel<<<dim3(4096), dim3(256), 0, stream>>>(w1, Wb1, n4w,
                                                       cached ? flag : nullptr);
    if (cached) {
        cvt_w_kernel<<<dim3(4096), dim3(256), 0, stream>>>(w2, Wb2, n4w, flag);
        set_flag_kernel<<<dim3(1), dim3(64), 0, stream>>>(flag);
    }

    router_kernel<<<dim3(TT / 4), dim3(256), 0, stream>>>(x, wr, tokE, tokW, counts);
    init_setup_kernel<<<dim3(ROWCAP / 256 + 1), dim3(256), 0, stream>>>(
        counts, cursor, tileExpert, tileRow0, rowTok);
    scatter_kernel<<<dim3(TT / 256), dim3(256), 0, stream>>>(tokE, cursor, rowTok, posOf);
    gather_kernel<<<dim3(ROWCAP), dim3(256), 0, stream>>>(x, rowTok, Xg);

    // FC1: H1g = gelu(Xg @ w1[e]^T + b1[e]);  256x256 tiles, waves 2x4
    gemm8<0, DFF, HD, 256, 2, 4><<<dim3(MAXTILES, DFF / 256), dim3(512), 0, stream>>>(
        Xg, Wb1, tileExpert, tileRow0, H1g, b1);

    // FC2: Yg = H1g @ w2[e]^T + b2[e];  256x128 tiles, waves 4x2
    if (!cached) {
        cvt_w_kernel<<<dim3(4096), dim3(256), 0, stream>>>(w2, Wb1, n4w, nullptr);
    }
    gemm8<1, HD, DFF, 128, 4, 2><<<dim3(MAXTILES, HD / 128), dim3(512), 0, stream>>>(
        H1g, Wb2, tileExpert, tileRow0, Yg, b2);

    // combine: out[t] = w0 * Yg[pos0(t)] + w1 * Yg[pos1(t)]
    combine_kernel<<<dim3(TT), dim3(256), 0, stream>>>(Yg, posOf, tokW, out);
}

// Round 3
// 1065.569 us; speedup vs baseline: 1.1183x; 1.0121x over previous
//
#include <hip/hip_runtime.h>
#include <hip/hip_bf16.h>
#include <math.h>

// MoE MLP: B=4, S=2048, H=1024, D_FF=4096, E=8, top-2.
// Round 5:
//  - router: read-once x, w_router in LDS, 8 fp64 accumulators (same summation
//    order as verified router -> bit-identical top-k).
//  - FC1: 128x128 tile, BK=32, 3-buffer LDS with TRUE counted vmcnt(4) across
//    the per-tile barrier (tile t stages t+2; never drains to 0 in-loop),
//    T2 XOR-swizzle (slot^(row&3), both-sides involution). 3 blocks/CU.
//  - FC2: round-2 gemm8 (256x128, 8-phase-ish) verbatim -- best measured.
//  - weight cvt: no caching flag (re-poison defeats it); both weights upfront
//    in one pass when ws >= 326 MB, else round-1 layout + mid-stream w2 cvt.

#define TT  8192    // tokens = B*S
#define HD  1024    // hidden
#define DFF 4096    // ffn dim
#define NE  8       // experts
#define ROWCAP 18432   // 16384 gathered rows + per-expert pad to 256 (<= 18424)
#define MAXT128 144    // sum padded/128 <= 18432/128
#define MAXT256 72     // sum padded/256 <= 72

typedef __attribute__((ext_vector_type(8))) short short8;
typedef __attribute__((ext_vector_type(4))) float f32x4;

// fp32 -> bf16 round-to-nearest-even (finite inputs)
static __device__ __forceinline__ unsigned short f2bf(float f) {
    unsigned int u = __float_as_uint(f);
    unsigned int r = (u + 0x7fffu + ((u >> 16) & 1u)) >> 16;
    return (unsigned short)r;
}

static __device__ __forceinline__ float bf2f(unsigned short u) {
    return __uint_as_float((unsigned int)u << 16);
}

// gelu tanh-form via sigmoid: v * sigmoid(1.5957691*(v + 0.044715 v^3)).
static __device__ __forceinline__ float gelu_fast(float v) {
    const float s = v * (1.5957691f + 0.07135481f * v * v);
    return v / (1.f + __expf(-s));
}

// async global->LDS, 16 bytes per lane. LDS dest = wave-uniform base + lane*16.
static __device__ __forceinline__ void gload_lds16(const void* gp, void* lp) {
    __builtin_amdgcn_global_load_lds(
        (__attribute__((address_space(1))) void*)(void*)gp,
        (__attribute__((address_space(3))) void*)lp,
        16, 0, 0);
}

// ------------------------------------------------------------- weights -> bf16
__global__ __launch_bounds__(256) void cvt_w_kernel(const float* __restrict__ s,
                                                    unsigned short* __restrict__ d,
                                                    long n4) {
    for (long i = (long)blockIdx.x * 256 + threadIdx.x; i < n4;
         i += (long)gridDim.x * 256) {
        float4 v = ((const float4*)s)[i];
        ushort4 o;
        o.x = f2bf(v.x); o.y = f2bf(v.y); o.z = f2bf(v.z); o.w = f2bf(v.w);
        ((ushort4*)d)[i] = o;
    }
}

// ------------------------------------------------------------- router
// One wave per token. x row read ONCE; w_router staged in LDS; 8 fp64
// accumulators per lane. Summation order and butterfly identical to the
// verified per-expert router -> bit-identical logits/top-k.
__global__ __launch_bounds__(256) void router_kernel(const float* __restrict__ x,
                                                     const float* __restrict__ wr,
                                                     int* __restrict__ tokE,
                                                     float* __restrict__ tokW,
                                                     int* __restrict__ counts) {
    __shared__ float wrs[NE * HD];  // 32 KB
    const int tid = threadIdx.x;
#pragma unroll
    for (int i = 0; i < NE * HD / 4 / 256; ++i)
        ((float4*)wrs)[i * 256 + tid] = ((const float4*)wr)[i * 256 + tid];
    __syncthreads();

    const int token = blockIdx.x * 4 + (tid >> 6);
    const int lane = tid & 63;
    const float* xp = x + (long)token * HD;
    double lg[NE];
#pragma unroll
    for (int e = 0; e < NE; ++e) lg[e] = 0.0;
    for (int i = lane; i < HD; i += 64) {
        const double xv = (double)xp[i];
#pragma unroll
        for (int e = 0; e < NE; ++e) lg[e] += xv * (double)wrs[e * HD + i];
    }
#pragma unroll
    for (int e = 0; e < NE; ++e) {
        double s = lg[e];
#pragma unroll
        for (int off = 32; off > 0; off >>= 1) s += __shfl_xor(s, off, 64);
        lg[e] = s;
    }
    if (lane == 0) {
        int i0 = 0; double v0 = lg[0];
#pragma unroll
        for (int e = 1; e < NE; ++e) if (lg[e] > v0) { v0 = lg[e]; i0 = e; }
        int i1 = -1; double v1 = -1e300;
#pragma unroll
        for (int e = 0; e < NE; ++e) if (e != i0 && lg[e] > v1) { v1 = lg[e]; i1 = e; }
        double p = exp(v1 - v0);  // v1 <= v0
        double d = 1.0 + p;
        tokE[token * 2] = i0;     tokW[token * 2] = (float)(1.0 / d);
        tokE[token * 2 + 1] = i1; tokW[token * 2 + 1] = (float)(p / d);
        atomicAdd(&counts[i0], 1);
        atomicAdd(&counts[i1], 1);
    }
}

// ------------------------------------------------------------- init + tile maps
// Pad each expert to 256 rows; build BOTH the 128-row map (FC1) and the
// 256-row map (FC2). Also default rowTok = 0 for pad rows.
__global__ __launch_bounds__(256) void init_setup_kernel(const int* __restrict__ counts,
                                                         int* __restrict__ cursor,
                                                         int* __restrict__ tE128,
                                                         int* __restrict__ tR128,
                                                         int* __restrict__ tE256,
                                                         int* __restrict__ tR256,
                                                         int* __restrict__ rowTok) {
    const int i = blockIdx.x * 256 + threadIdx.x;
    if (i < ROWCAP) rowTok[i] = 0;
    if (blockIdx.x == gridDim.x - 1 && threadIdx.x == 0) {
        int off = 0, a = 0, b = 0;
        for (int e = 0; e < NE; ++e) {
            cursor[e] = off;
            const int padded = (counts[e] + 255) & ~255;
            for (int j = 0; j < padded / 128; ++j) {
                tE128[a] = e; tR128[a] = off + j * 128; ++a;
            }
            for (int j = 0; j < padded / 256; ++j) {
                tE256[b] = e; tR256[b] = off + j * 256; ++b;
            }
            off += padded;
        }
        for (; a < MAXT128; ++a) tE128[a] = -1;
        for (; b < MAXT256; ++b) tE256[b] = -1;
    }
}

// scatter: fill row->token map AND the inverse map token->row position
__global__ __launch_bounds__(256) void scatter_kernel(const int* __restrict__ tokE,
                                                      int* __restrict__ cursor,
                                                      int* __restrict__ rowTok,
                                                      int* __restrict__ posOf) {
    const int t = blockIdx.x * 256 + threadIdx.x;
#pragma unroll
    for (int j = 0; j < 2; ++j) {
        const int e = tokE[t * 2 + j];
        const int pos = atomicAdd(&cursor[e], 1);
        rowTok[pos] = t;
        posOf[t * 2 + j] = pos;
    }
}

// gather + cvt: Xg[row][:] = bf16(x[rowTok[row]][:])
__global__ __launch_bounds__(256) void gather_kernel(const float* __restrict__ x,
                                                     const int* __restrict__ rowTok,
                                                     unsigned short* __restrict__ Xg) {
    const int row = blockIdx.x;
    const int tok = rowTok[row];
    const float4 v = ((const float4*)(x + (long)tok * HD))[threadIdx.x];
    ushort4 o;
    o.x = f2bf(v.x); o.y = f2bf(v.y); o.z = f2bf(v.z); o.w = f2bf(v.w);
    ((ushort4*)(Xg + (long)row * HD))[threadIdx.x] = o;
}

// ------------------------------------------------------------- FC1 GEMM
// 128x128 tile, BK=32, 3-buffer LDS, counted vmcnt(4) across the per-tile
// barrier (tile t stages tile t+2; 4 loads stay in flight across barriers).
// T2 swizzle: LDS slot s of row m holds global slot s^(m&3); read slot
// quad^(m&3). Hout = bf16(gelu(C + bias)).
template <int N, int K>
__global__ __launch_bounds__(256) void gemm_fc1(
    const unsigned short* __restrict__ A,
    const unsigned short* __restrict__ W,
    const int* __restrict__ tE,
    const int* __restrict__ tR,
    unsigned short* __restrict__ Hout,
    const float* __restrict__ bias) {
    constexpr int BK = 32, NT = K / BK;
    const int e = tE[blockIdx.x];
    if (e < 0) return;

    __shared__ unsigned short As[3][128 * BK];  // 3 x 8 KB
    __shared__ unsigned short Bs[3][128 * BK];  // 3 x 8 KB

    const int tid = threadIdx.x;
    const int lane = tid & 63;
    const int quad = lane >> 4;
    const int l15 = lane & 15;
    const int wy = (tid >> 6) >> 1;
    const int wx = (tid >> 6) & 1;
    const long row0 = tR[blockIdx.x];
    const long n0 = (long)blockIdx.y * 128;
    const unsigned short* Ab = A + row0 * K;
    const unsigned short* Bb = W + ((long)e * N + n0) * K;

    // staging chunks: c = it*256+tid; row m=c>>2, slot s=c&3; source k-chunk
    // pre-swizzled (s^(m&3)) so linear LDS dest + XOR read are consistent.
    const int c0 = tid, c1 = 256 + tid;
    const int m0 = c0 >> 2, s0 = c0 & 3;
    const int m1 = c1 >> 2, s1 = c1 & 3;
    const long aoff0 = (long)m0 * K + (s0 ^ (m0 & 3)) * 8;
    const long aoff1 = (long)m1 * K + (s1 ^ (m1 & 3)) * 8;

    f32x4 acc[4][4];
#pragma unroll
    for (int i = 0; i < 4; ++i)
#pragma unroll
        for (int j = 0; j < 4; ++j) acc[i][j] = (f32x4){0.f, 0.f, 0.f, 0.f};

    auto STG = [&](int b, int t) {
        const long k0 = (long)t * BK;
        gload_lds16(Ab + aoff0 + k0, As[b] + c0 * 8);
        gload_lds16(Ab + aoff1 + k0, As[b] + c1 * 8);
        gload_lds16(Bb + aoff0 + k0, Bs[b] + c0 * 8);
        gload_lds16(Bb + aoff1 + k0, Bs[b] + c1 * 8);
    };

    STG(0, 0);
    STG(1, 1);
    asm volatile("s_waitcnt vmcnt(4)" ::: "memory");  // tile 0 landed; tile 1 in flight
    __builtin_amdgcn_s_barrier();
    __builtin_amdgcn_sched_barrier(0);

    const int sw = (quad ^ (l15 & 3)) * 8;  // (row&3) == (l15&3) for all frag rows

#pragma unroll 1
    for (int t = 0; t < NT; ++t) {
        const int cur = t % 3;
        if (t + 2 < NT) STG((t + 2) % 3, t + 2);

        const unsigned short* Ac = As[cur];
        const unsigned short* Bc = Bs[cur];
        short8 af[4], bf[4];
#pragma unroll
        for (int mi = 0; mi < 4; ++mi)
            af[mi] = *(const short8*)(Ac + (wy * 64 + mi * 16 + l15) * BK + sw);
#pragma unroll
        for (int ni = 0; ni < 4; ++ni)
            bf[ni] = *(const short8*)(Bc + (wx * 64 + ni * 16 + l15) * BK + sw);
        __builtin_amdgcn_s_setprio(1);
#pragma unroll
        for (int ni = 0; ni < 4; ++ni)
#pragma unroll
            for (int mi = 0; mi < 4; ++mi)
                acc[mi][ni] = __builtin_amdgcn_mfma_f32_16x16x32_bf16(
                    af[mi], bf[ni], acc[mi][ni], 0, 0, 0);
        __builtin_amdgcn_s_setprio(0);

        // drain own ds_reads (WAR vs next writes), keep t+2's 4 loads in
        // flight across the barrier (counted vmcnt, T4), ensure t+1 landed.
        asm volatile("s_waitcnt lgkmcnt(0)" ::: "memory");
        __builtin_amdgcn_sched_barrier(0);
        if (t + 2 < NT)
            asm volatile("s_waitcnt vmcnt(4)" ::: "memory");
        else
            asm volatile("s_waitcnt vmcnt(0)" ::: "memory");
        __builtin_amdgcn_s_barrier();
        __builtin_amdgcn_sched_barrier(0);
    }

    // epilogue: C/D layout row = quad*4 + r, col = l15 (verified m89/m91)
#pragma unroll
    for (int mi = 0; mi < 4; ++mi) {
        const int lrow0 = wy * 64 + mi * 16 + quad * 4;
#pragma unroll
        for (int ni = 0; ni < 4; ++ni) {
            const long col = n0 + wx * 64 + ni * 16 + l15;
            const float bcol = bias[(long)e * N + col];
#pragma unroll
            for (int r = 0; r < 4; ++r) {
                const long grow = row0 + lrow0 + r;
                const float v = acc[mi][ni][r] + bcol;
                Hout[grow * N + col] = f2bf(gelu_fast(v));
            }
        }
    }
}

// ------------------------------------------------------------- FC2 GEMM
// Round-2 gemm8 verbatim (256-row tile, BK=64, 8 waves 4x2, BN=128,
// double-buffered LDS, quadrant phases, counted vmcnt, T2 swizzle, setprio).
template <int N, int K, int BN, int WM, int WN>
__global__ __launch_bounds__(512, 2) void gemm8(
    const unsigned short* __restrict__ A,
    const unsigned short* __restrict__ W,
    const int* __restrict__ tileExpert,
    const int* __restrict__ tileRow0,
    unsigned short* __restrict__ Hout,
    const float* __restrict__ bias) {
    constexpr int BM = 256, BK = 64;
    constexpr int NT = K / BK;
    constexpr int MREP = BM / WM / 16;
    constexpr int NREP = BN / WN / 16;
    constexpr int MIQ = MREP / 4;
    constexpr int ACH = BM * BK / (512 * 8);
    constexpr int BCH = BN * BK / (512 * 8);
    constexpr int HALF = (BM + BN) * BK;

    const int e = tileExpert[blockIdx.x];
    if (e < 0) return;

    __shared__ unsigned short smem[2 * HALF];

    const int tid = threadIdx.x;
    const int lane = tid & 63;
    const int quad = lane >> 4;
    const int l15 = lane & 15;
    const int wid = tid >> 6;
    const int wr = wid / WN;
    const int wc = wid % WN;
    const int axor = (l15 & 7) << 4;

    const long row0 = tileRow0[blockIdx.x];
    const long n0 = (long)blockIdx.y * BN;
    const unsigned short* Ab = A + row0 * K;
    const unsigned short* Bb = W + ((long)e * N + n0) * K;

    const unsigned short* aS[ACH];
    const unsigned short* bS[BCH];
    int aD[ACH], bD[BCH];
#pragma unroll
    for (int i = 0; i < ACH; ++i) {
        const int c = i * 512 + tid, r = c >> 3, s = c & 7;
        aS[i] = Ab + (long)r * K + (s ^ (r & 7)) * 8;
        aD[i] = c * 8;
    }
#pragma unroll
    for (int i = 0; i < BCH; ++i) {
        const int c = i * 512 + tid, r = c >> 3, s = c & 7;
        bS[i] = Bb + (long)r * K + (s ^ (r & 7)) * 8;
        bD[i] = c * 8;
    }

    f32x4 acc[MREP][NREP];
#pragma unroll
    for (int i = 0; i < MREP; ++i)
#pragma unroll
        for (int j = 0; j < NREP; ++j) acc[i][j] = (f32x4){0.f, 0.f, 0.f, 0.f};

    auto STAGE = [&](int buf, int t) {
        unsigned short* dst = smem + buf * HALF;
#pragma unroll
        for (int i = 0; i < ACH; ++i)
            gload_lds16(aS[i] + (long)t * BK, dst + aD[i]);
        unsigned short* dstB = dst + BM * BK;
#pragma unroll
        for (int i = 0; i < BCH; ++i)
            gload_lds16(bS[i] + (long)t * BK, dstB + bD[i]);
    };

    STAGE(0, 0);
#pragma unroll 1
    for (int t = 0; t < NT; ++t) {
        const int cur = t & 1;
        if (t + 1 < NT) {
            STAGE(cur ^ 1, t + 1);
            asm volatile("s_waitcnt vmcnt(%0)" ::"n"(ACH + BCH) : "memory");
        } else {
            asm volatile("s_waitcnt vmcnt(0)" ::: "memory");
        }
        __builtin_amdgcn_s_barrier();
        asm volatile("" ::: "memory");

        const unsigned short* Abuf = smem + cur * HALF;
        const unsigned short* Bbuf = Abuf + BM * BK;
        short8 bfr[NREP][2];
#pragma unroll
        for (int q = 0; q < 4; ++q) {
            if (q == 0) {
#pragma unroll
                for (int ni = 0; ni < NREP; ++ni)
#pragma unroll
                    for (int ks = 0; ks < 2; ++ks) {
                        const int rowb = wc * (BN / WN) + ni * 16 + l15;
                        bfr[ni][ks] = *(const short8*)((const char*)Bbuf +
                            ((rowb * (BK * 2) + ks * 64 + quad * 16) ^ axor));
                    }
            }
            short8 afr[MIQ][2];
#pragma unroll
            for (int i = 0; i < MIQ; ++i)
#pragma unroll
                for (int ks = 0; ks < 2; ++ks) {
                    const int rowa = wr * (BM / WM) + (q * MIQ + i) * 16 + l15;
                    afr[i][ks] = *(const short8*)((const char*)Abuf +
                        ((rowa * (BK * 2) + ks * 64 + quad * 16) ^ axor));
                }
            __builtin_amdgcn_s_setprio(1);
#pragma unroll
            for (int i = 0; i < MIQ; ++i)
#pragma unroll
                for (int ni = 0; ni < NREP; ++ni)
#pragma unroll
                    for (int ks = 0; ks < 2; ++ks)
                        acc[q * MIQ + i][ni] = __builtin_amdgcn_mfma_f32_16x16x32_bf16(
                            afr[i][ks], bfr[ni][ks], acc[q * MIQ + i][ni], 0, 0, 0);
            __builtin_amdgcn_s_setprio(0);
            __builtin_amdgcn_s_barrier();
            asm volatile("" ::: "memory");
        }
    }

#pragma unroll
    for (int mi = 0; mi < MREP; ++mi) {
        const long grow0 = row0 + wr * (BM / WM) + mi * 16 + quad * 4;
#pragma unroll
        for (int ni = 0; ni < NREP; ++ni) {
            const long col = n0 + wc * (BN / WN) + ni * 16 + l15;
            const float bcol = bias[(long)e * N + col];
#pragma unroll
            for (int r = 0; r < 4; ++r) {
                const float v = acc[mi][ni][r] + bcol;
                Hout[(grow0 + r) * N + col] = f2bf(v);
            }
        }
    }
}

// ------------------------------------------------------------- combine
__global__ __launch_bounds__(256) void combine_kernel(const unsigned short* __restrict__ Y,
                                                      const int* __restrict__ posOf,
                                                      const float* __restrict__ tokW,
                                                      float* __restrict__ out) {
    const int t = blockIdx.x;
    const int p0 = posOf[t * 2];
    const int p1 = posOf[t * 2 + 1];
    const float w0 = tokW[t * 2];
    const float w1 = tokW[t * 2 + 1];
    const ushort4 a = ((const ushort4*)(Y + (long)p0 * HD))[threadIdx.x];
    const ushort4 b = ((const ushort4*)(Y + (long)p1 * HD))[threadIdx.x];
    float4 o;
    o.x = w0 * bf2f(a.x) + w1 * bf2f(b.x);
    o.y = w0 * bf2f(a.y) + w1 * bf2f(b.y);
    o.z = w0 * bf2f(a.z) + w1 * bf2f(b.z);
    o.w = w0 * bf2f(a.w) + w1 * bf2f(b.w);
    ((float4*)(out + (long)t * HD))[threadIdx.x] = o;
}

// ------------------------------------------------------------- launch
extern "C" void kernel_launch(void* const* d_in, const int* in_sizes, int n_in,
                              void* d_out, int out_size, void* d_ws, size_t ws_size,
                              hipStream_t stream) {
    const float* x  = (const float*)d_in[0];   // [4,2048,1024]
    const float* wr = (const float*)d_in[1];   // [8,1024]
    const float* w1 = (const float*)d_in[2];   // [8,4096,1024]
    const float* b1 = (const float*)d_in[3];   // [8,4096]
    const float* w2 = (const float*)d_in[4];   // [8,1024,4096]
    const float* b2 = (const float*)d_in[5];   // [8,1024]
    float* out = (float*)d_out;                // [4,2048,1024] fp32

    const size_t WBYTES = (size_t)NE * DFF * HD * 2;  // 67.1 MB per weight
    // full layout ~323.5 MB (separate Wb2); fallback ~256.3 MB (shared Wb).
    const bool full = ws_size >= (size_t)326 * 1024 * 1024;

    char* p = (char*)d_ws;
    auto alloc = [&](size_t bytes) {
        char* r = p;
        p += (bytes + 255) & ~(size_t)255;
        return r;
    };
    unsigned short* Xg  = (unsigned short*)alloc((size_t)ROWCAP * HD * 2);   // 37.7 MB
    unsigned short* H1g = (unsigned short*)alloc((size_t)ROWCAP * DFF * 2);  // 151 MB
    unsigned short* Wb1 = (unsigned short*)alloc(WBYTES);                    // 67.1 MB
    unsigned short* Wb2 = full ? (unsigned short*)alloc(WBYTES) : Wb1;
    int*   rowTok  = (int*)alloc((size_t)ROWCAP * 4);
    int*   posOf   = (int*)alloc((size_t)TT * 2 * 4);
    int*   tokE    = (int*)alloc((size_t)TT * 2 * 4);
    float* tokW    = (float*)alloc((size_t)TT * 2 * 4);
    int*   counts  = (int*)alloc(64);
    int*   cursor  = (int*)alloc(64);
    int*   tE128   = (int*)alloc(MAXT128 * 4);
    int*   tR128   = (int*)alloc(MAXT128 * 4);
    int*   tE256   = (int*)alloc(MAXT256 * 4);
    int*   tR256   = (int*)alloc(MAXT256 * 4);

    // Yg (FC2 per-row bf16 output) reuses the Xg slot (Xg dead after FC1;
    // distinct from Wb1/Wb2 in both paths).
    unsigned short* Yg = Xg;

    hipMemsetAsync(counts, 0, 64, stream);

    const long n4w = (long)NE * DFF * HD / 4;
    cvt_w_kernel<<<dim3(4096), dim3(256), 0, stream>>>(w1, Wb1, n4w);
    if (full)
        cvt_w_kernel<<<dim3(4096), dim3(256), 0, stream>>>(w2, Wb2, n4w);

    router_kernel<<<dim3(TT / 4), dim3(256), 0, stream>>>(x, wr, tokE, tokW, counts);
    init_setup_kernel<<<dim3(ROWCAP / 256 + 1), dim3(256), 0, stream>>>(
        counts, cursor, tE128, tR128, tE256, tR256, rowTok);
    scatter_kernel<<<dim3(TT / 256), dim3(256), 0, stream>>>(tokE, cursor, rowTok, posOf);
    gather_kernel<<<dim3(ROWCAP), dim3(256), 0, stream>>>(x, rowTok, Xg);

    // FC1: H1g = gelu(Xg @ w1[e]^T + b1[e]);  128x128 tiles, counted-vmcnt pipe
    gemm_fc1<DFF, HD><<<dim3(MAXT128, DFF / 128), dim3(256), 0, stream>>>(
        Xg, Wb1, tE128, tR128, H1g, b1);

    // FC2: Yg = H1g @ w2[e]^T + b2[e];  256x128 tiles, 8 waves 4x2
    if (!full)
        cvt_w_kernel<<<dim3(4096), dim3(256), 0, stream>>>(w2, Wb1, n4w);
    gemm8<HD, DFF, 128, 4, 2><<<dim3(MAXT256, HD / 128), dim3(512), 0, stream>>>(
        H1g, Wb2, tE256, tR256, Yg, b2);

    // combine: out[t] = w0 * Yg[pos0(t)] + w1 * Yg[pos1(t)]
    combine_kernel<<<dim3(TT), dim3(256), 0, stream>>>(Yg, posOf, tokW, out);
}

// Round 4
// 1014.909 us; speedup vs baseline: 1.1741x; 1.0499x over previous
//
#include <hip/hip_runtime.h>
#include <hip/hip_bf16.h>
#include <math.h>

// MoE MLP: B=4, S=2048, H=1024, D_FF=4096, E=8, top-2.
// Round 6: faithful fine-interleaved 4-phase/K-tile schedule (m201-style) for
// BOTH GEMMs: per phase {ds_read half | stage ONE half-tile | bar | lgkm0 |
// setprio MFMA | counted vmcnt | bar}; vmcnt never 0 in main loop (T3+T4),
// zero-conflict 128B-row XOR swizzle (T2, proven in R2), setprio (T5),
// XCD-bijective block swizzle (T1). B-halves LDS-row-permuted so staging
// stays contiguous while halves match wave fragment consumption.

#define TT  8192    // tokens = B*S
#define HD  1024    // hidden
#define DFF 4096    // ffn dim
#define NE  8       // experts
#define ROWCAP 18432   // gathered rows, per-expert pad to 256
#define MAXT 72        // sum ceil(counts[e]/256) <= 72

typedef __attribute__((ext_vector_type(8))) short short8;
typedef __attribute__((ext_vector_type(4))) float f32x4;

// fp32 -> bf16 round-to-nearest-even (finite inputs)
static __device__ __forceinline__ unsigned short f2bf(float f) {
    unsigned int u = __float_as_uint(f);
    unsigned int r = (u + 0x7fffu + ((u >> 16) & 1u)) >> 16;
    return (unsigned short)r;
}

static __device__ __forceinline__ float bf2f(unsigned short u) {
    return __uint_as_float((unsigned int)u << 16);
}

// gelu tanh-form via sigmoid: v * sigmoid(1.5957691*(v + 0.044715 v^3)).
static __device__ __forceinline__ float gelu_fast(float v) {
    const float s = v * (1.5957691f + 0.07135481f * v * v);
    return v / (1.f + __expf(-s));
}

// async global->LDS, 16 bytes per lane. LDS dest = wave-uniform base + lane*16.
static __device__ __forceinline__ void gload_lds16(const void* gp, void* lp) {
    __builtin_amdgcn_global_load_lds(
        (__attribute__((address_space(1))) void*)(void*)gp,
        (__attribute__((address_space(3))) void*)lp,
        16, 0, 0);
}

#define BARM                                        \
    __builtin_amdgcn_s_barrier();                   \
    asm volatile("" ::: "memory");                  \
    __builtin_amdgcn_sched_barrier(0)
#define LGKM0                                       \
    asm volatile("s_waitcnt lgkmcnt(0)" ::: "memory"); \
    __builtin_amdgcn_sched_barrier(0)
#define PRIO1 __builtin_amdgcn_s_setprio(1)
#define PRIO0 __builtin_amdgcn_s_setprio(0)

// ------------------------------------------------------------- weights -> bf16
// both weights in one dispatch (one less launch)
__global__ __launch_bounds__(256) void cvt_w2_kernel(const float* __restrict__ s1,
                                                     unsigned short* __restrict__ d1,
                                                     const float* __restrict__ s2,
                                                     unsigned short* __restrict__ d2,
                                                     long n4) {
    for (long i = (long)blockIdx.x * 256 + threadIdx.x; i < 2 * n4;
         i += (long)gridDim.x * 256) {
        const bool second = i >= n4;
        const long j = second ? i - n4 : i;
        float4 v = second ? ((const float4*)s2)[j] : ((const float4*)s1)[j];
        ushort4 o;
        o.x = f2bf(v.x); o.y = f2bf(v.y); o.z = f2bf(v.z); o.w = f2bf(v.w);
        if (second) ((ushort4*)d2)[j] = o; else ((ushort4*)d1)[j] = o;
    }
}

__global__ __launch_bounds__(256) void cvt_w_kernel(const float* __restrict__ s,
                                                    unsigned short* __restrict__ d,
                                                    long n4) {
    for (long i = (long)blockIdx.x * 256 + threadIdx.x; i < n4;
         i += (long)gridDim.x * 256) {
        float4 v = ((const float4*)s)[i];
        ushort4 o;
        o.x = f2bf(v.x); o.y = f2bf(v.y); o.z = f2bf(v.z); o.w = f2bf(v.w);
        ((ushort4*)d)[i] = o;
    }
}

// ------------------------------------------------------------- router
// One wave per token; x read once, w_router in LDS, fp64 accumulation with
// the verified summation order (bit-identical top-k vs reference ordering).
__global__ __launch_bounds__(256) void router_kernel(const float* __restrict__ x,
                                                     const float* __restrict__ wr,
                                                     int* __restrict__ tokE,
                                                     float* __restrict__ tokW,
                                                     int* __restrict__ counts) {
    __shared__ float wrs[NE * HD];  // 32 KB
    const int tid = threadIdx.x;
#pragma unroll
    for (int i = 0; i < NE * HD / 4 / 256; ++i)
        ((float4*)wrs)[i * 256 + tid] = ((const float4*)wr)[i * 256 + tid];
    __syncthreads();

    const int token = blockIdx.x * 4 + (tid >> 6);
    const int lane = tid & 63;
    const float* xp = x + (long)token * HD;
    double lg[NE];
#pragma unroll
    for (int e = 0; e < NE; ++e) lg[e] = 0.0;
    for (int i = lane; i < HD; i += 64) {
        const double xv = (double)xp[i];
#pragma unroll
        for (int e = 0; e < NE; ++e) lg[e] += xv * (double)wrs[e * HD + i];
    }
#pragma unroll
    for (int e = 0; e < NE; ++e) {
        double s = lg[e];
#pragma unroll
        for (int off = 32; off > 0; off >>= 1) s += __shfl_xor(s, off, 64);
        lg[e] = s;
    }
    if (lane == 0) {
        int i0 = 0; double v0 = lg[0];
#pragma unroll
        for (int e = 1; e < NE; ++e) if (lg[e] > v0) { v0 = lg[e]; i0 = e; }
        int i1 = -1; double v1 = -1e300;
#pragma unroll
        for (int e = 0; e < NE; ++e) if (e != i0 && lg[e] > v1) { v1 = lg[e]; i1 = e; }
        double p = exp(v1 - v0);  // v1 <= v0
        double d = 1.0 + p;
        tokE[token * 2] = i0;     tokW[token * 2] = (float)(1.0 / d);
        tokE[token * 2 + 1] = i1; tokW[token * 2 + 1] = (float)(p / d);
        atomicAdd(&counts[i0], 1);
        atomicAdd(&counts[i1], 1);
    }
}

// ------------------------------------------------------------- init + tile map
__global__ __launch_bounds__(256) void init_setup_kernel(const int* __restrict__ counts,
                                                         int* __restrict__ cursor,
                                                         int* __restrict__ tE,
                                                         int* __restrict__ tR,
                                                         int* __restrict__ rowTok) {
    const int i = blockIdx.x * 256 + threadIdx.x;
    if (i < ROWCAP) rowTok[i] = 0;
    if (blockIdx.x == gridDim.x - 1 && threadIdx.x == 0) {
        int off = 0, t = 0;
        for (int e = 0; e < NE; ++e) {
            cursor[e] = off;
            const int padded = (counts[e] + 255) & ~255;
            for (int j = 0; j < padded / 256; ++j) {
                tE[t] = e; tR[t] = off + j * 256; ++t;
            }
            off += padded;
        }
        for (; t < MAXT; ++t) tE[t] = -1;
    }
}

// scatter: row->token map AND inverse token->position map
__global__ __launch_bounds__(256) void scatter_kernel(const int* __restrict__ tokE,
                                                      int* __restrict__ cursor,
                                                      int* __restrict__ rowTok,
                                                      int* __restrict__ posOf) {
    const int t = blockIdx.x * 256 + threadIdx.x;
#pragma unroll
    for (int j = 0; j < 2; ++j) {
        const int e = tokE[t * 2 + j];
        const int pos = atomicAdd(&cursor[e], 1);
        rowTok[pos] = t;
        posOf[t * 2 + j] = pos;
    }
}

// gather + cvt: Xg[row][:] = bf16(x[rowTok[row]][:])
__global__ __launch_bounds__(256) void gather_kernel(const float* __restrict__ x,
                                                     const int* __restrict__ rowTok,
                                                     unsigned short* __restrict__ Xg) {
    const int row = blockIdx.x;
    const int tok = rowTok[row];
    const float4 v = ((const float4*)(x + (long)tok * HD))[threadIdx.x];
    ushort4 o;
    o.x = f2bf(v.x); o.y = f2bf(v.y); o.z = f2bf(v.z); o.w = f2bf(v.w);
    ((ushort4*)(Xg + (long)row * HD))[threadIdx.x] = o;
}

// ------------------------------------------------------------- grouped GEMM
// BM=256, BK=64, 8 waves (2 rows x 4 cols of 128x(BN/4) wave-tiles), double-
// buffered LDS. Per K-tile 4 phases: p0 (hm0,hn0), p1 (hm1,hn0), p2 (hm1,hn1),
// p3 (hm0,hn1). Each phase stages exactly one half-tile of tile t+1 and ends
// with a counted vmcnt (VB, never 0). Swizzle: 128B rows, 16B slot s of LDS
// row rho holds global slot s^(rho&7); reads XOR the same way (0 conflicts,
// verified R2). B LDS rows permuted so each staged half is LDS-contiguous
// while matching the fragment half actually consumed (rule #21 both-sides).
// C[m,n] = sum_k A[row0+m,k] * W[e][n0+n,k].
// EPI=0: Hout = bf16(gelu(C+bias));  EPI=1: Hout = bf16(C+bias).
template <int EPI, int N, int K, int BN>
__global__ __launch_bounds__(512, 2) void gemm4p(
    const unsigned short* __restrict__ A,
    const unsigned short* __restrict__ W,
    const int* __restrict__ tE,
    const int* __restrict__ tR,
    unsigned short* __restrict__ Hout,
    const float* __restrict__ bias) {
    constexpr int BM = 256, BK = 64, NT = K / BK;
    constexpr int NREP = BN / 64;     // frags per wave along N: 4 or 2
    constexpr int NREP2 = NREP / 2;   // per hn half: 2 or 1
    constexpr int NB = BN / 64;       // B loads/thread/tile: 4 or 2
    constexpr int NB2 = NB / 2;       // per B half: 2 or 1
    constexpr int HB = BN / 8;        // B half-select bit: 32 or 16
    constexpr int LOG2HB = (BN == 256) ? 5 : 4;
    constexpr int VB = NB2 + 2;       // counted vmcnt (4 or 3)
    constexpr int AHALF = BM * BK;    // ushorts
    constexpr int HALF = (BM + BN) * BK;

    // XCD-bijective swizzle: nwg = gridDim.x*gridDim.y is a multiple of 8
    // (72*16, 72*8). Same-y (same B panel) blocks stay on one XCD.
    const int nwg = gridDim.x * gridDim.y;
    int bid = blockIdx.y * gridDim.x + blockIdx.x;
    bid = (bid & 7) * (nwg >> 3) + (bid >> 3);
    const int tix = bid % gridDim.x;
    const int niy = bid / gridDim.x;

    const int e = tE[tix];
    if (e < 0) return;

    __shared__ unsigned short smem[2 * HALF];  // FC1 128 KB, FC2 96 KB

    const int tid = threadIdx.x;
    const int lane = tid & 63;
    const int quad = lane >> 4;
    const int l15 = lane & 15;
    const int wid = tid >> 6;
    const int wrr = wid >> 2;   // 0..1
    const int wcc = wid & 3;    // 0..3

    const long row0 = tR[tix];
    const long n0 = (long)niy * BN;
    const unsigned short* Ab = A + row0 * K;
    const unsigned short* Bb = W + ((long)e * N + n0) * K;

    // staging sources. A: chunk c=i*512+tid -> row c>>3, slot c&7 (identity
    // LDS rows; halves = loads {0,2} / {1,3}). B: LDS row rho = c>>3 maps to
    // global row r via the half-permutation; halves = first/second NB2 loads.
    const unsigned short* aS[4];
    int aD[4];
#pragma unroll
    for (int i = 0; i < 4; ++i) {
        const int c = i * 512 + tid;
        const int r = c >> 3, s = c & 7;
        aS[i] = Ab + (long)r * K + (s ^ (r & 7)) * 8;
        aD[i] = c * 8;
    }
    const unsigned short* bS[NB];
    int bD[NB];
#pragma unroll
    for (int i = 0; i < NB; ++i) {
        const int c = i * 512 + tid;
        const int rho = c >> 3, s = c & 7;
        const int rl = rho & (BN / 2 - 1);
        const int r = (rl & (HB - 1)) + ((rl >> LOG2HB) << (LOG2HB + 1)) +
                      ((rho >= BN / 2) ? HB : 0);
        bS[i] = Bb + (long)r * K + (s ^ (rho & 7)) * 8;
        bD[i] = c * 8;
    }

    auto stgA = [&](int buf, int t, int g) {  // g=0: loads 0,2 ; g=1: 1,3
        unsigned short* dst = smem + buf * HALF;
        gload_lds16(aS[g] + (long)t * BK, dst + aD[g]);
        gload_lds16(aS[g + 2] + (long)t * BK, dst + aD[g + 2]);
    };
    auto stgB = [&](int buf, int t, int g) {
        unsigned short* dst = smem + buf * HALF + AHALF;
#pragma unroll
        for (int j = 0; j < NB2; ++j)
            gload_lds16(bS[g * NB2 + j] + (long)t * BK, dst + bD[g * NB2 + j]);
    };
    auto rdA = [&](const unsigned short* Ac, int mi, int ks) -> short8 {
        const int row = wrr * 128 + mi * 16 + l15;
        return *(const short8*)(Ac + row * BK + ((ks * 4 + quad) ^ (row & 7)) * 8);
    };
    auto rdB = [&](const unsigned short* Bc, int ni, int ks) -> short8 {
        int rho;
        if constexpr (BN == 256)
            rho = (ni & 1) * 16 + l15 + wcc * 32 + ((ni & 2) ? 128 : 0);
        else
            rho = l15 + wcc * 16 + ni * 64;
        return *(const short8*)(Bc + rho * BK + ((ks * 4 + quad) ^ (rho & 7)) * 8);
    };

#define RD_A(AF, AC, HM)                                                \
    _Pragma("unroll") for (int i_ = 0; i_ < 4; ++i_)                    \
    _Pragma("unroll") for (int k_ = 0; k_ < 2; ++k_)                    \
        AF[i_][k_] = rdA(AC, (HM) * 4 + i_, k_);
#define RD_B(BF, BC, HN)                                                \
    _Pragma("unroll") for (int j_ = 0; j_ < NREP2; ++j_)                \
    _Pragma("unroll") for (int k_ = 0; k_ < 2; ++k_)                    \
        BF[j_][k_] = rdB(BC, (HN) * NREP2 + j_, k_);
#define MMA_Q(AF, BF, HM, HN)                                           \
    _Pragma("unroll") for (int i_ = 0; i_ < 4; ++i_)                    \
    _Pragma("unroll") for (int j_ = 0; j_ < NREP2; ++j_)                \
    _Pragma("unroll") for (int k_ = 0; k_ < 2; ++k_)                    \
        acc[(HM) * 4 + i_][(HN) * NREP2 + j_] =                         \
            __builtin_amdgcn_mfma_f32_16x16x32_bf16(                    \
                AF[i_][k_], BF[j_][k_],                                 \
                acc[(HM) * 4 + i_][(HN) * NREP2 + j_], 0, 0, 0);
#define VMC(NN) asm volatile("s_waitcnt vmcnt(%0)" ::"n"(NN) : "memory")

    f32x4 acc[8][NREP];
#pragma unroll
    for (int i = 0; i < 8; ++i)
#pragma unroll
        for (int j = 0; j < NREP; ++j) acc[i][j] = (f32x4){0.f, 0.f, 0.f, 0.f};

    // prologue: stage tile 0 in group order G0(A-h0) G1(B-h0) G2(A-h1) G3(B-h1)
    stgA(0, 0, 0); stgB(0, 0, 0); stgA(0, 0, 1); stgB(0, 0, 1);
    VMC(VB);   // G0,G1 landed; G2,G3 (= VB loads) still in flight
    BARM;

#pragma unroll 1
    for (int t = 0; t < NT - 1; ++t) {
        const int cur = t & 1;
        const int nb = cur ^ 1;
        const unsigned short* Ac = smem + cur * HALF;
        const unsigned short* Bc = Ac + AHALF;
        short8 af0[4][2], af1[4][2], bf0[NREP2][2], bf1[NREP2][2];
        // phase 0: (hm0, hn0)
        RD_A(af0, Ac, 0); RD_B(bf0, Bc, 0);
        stgA(nb, t + 1, 0);
        BARM; LGKM0;
        PRIO1; MMA_Q(af0, bf0, 0, 0); PRIO0;
        VMC(VB); BARM;        // G2(t) landed for phase 1's A reads
        // phase 1: (hm1, hn0)
        RD_A(af1, Ac, 1);
        stgB(nb, t + 1, 0);
        BARM; LGKM0;
        PRIO1; MMA_Q(af1, bf0, 1, 0); PRIO0;
        VMC(VB); BARM;        // G3(t) landed for phase 2's B reads
        // phase 2: (hm1, hn1)
        RD_B(bf1, Bc, 1);
        stgA(nb, t + 1, 1);
        BARM; LGKM0;
        PRIO1; MMA_Q(af1, bf1, 1, 1); PRIO0;
        BARM;                 // no vmcnt: phase 3 reads nothing
        // phase 3: (hm0, hn1)
        stgB(nb, t + 1, 1);
        BARM;
        PRIO1; MMA_Q(af0, bf1, 0, 1); PRIO0;
        VMC(VB); BARM;        // G0,G1 of t+1 landed for next p0
    }

    {   // peeled last tile (no staging)
        const int cur = (NT - 1) & 1;
        const unsigned short* Ac = smem + cur * HALF;
        const unsigned short* Bc = Ac + AHALF;
        short8 af0[4][2], af1[4][2], bf0[NREP2][2], bf1[NREP2][2];
        RD_A(af0, Ac, 0); RD_B(bf0, Bc, 0);
        BARM; LGKM0;
        PRIO1; MMA_Q(af0, bf0, 0, 0); PRIO0;
        VMC(NB2); BARM;       // G2 landed; G3 still out
        RD_A(af1, Ac, 1);
        BARM; LGKM0;
        PRIO1; MMA_Q(af1, bf0, 1, 0); PRIO0;
        VMC(0); BARM;         // G3 landed
        RD_B(bf1, Bc, 1);
        BARM; LGKM0;
        PRIO1; MMA_Q(af1, bf1, 1, 1); PRIO0;
        PRIO1; MMA_Q(af0, bf1, 0, 1); PRIO0;
    }

    // epilogue: C/D layout row = quad*4 + r, col = l15 (verified m89/m91)
#pragma unroll
    for (int mi = 0; mi < 8; ++mi) {
        const long grow0 = row0 + wrr * 128 + mi * 16 + quad * 4;
#pragma unroll
        for (int ni = 0; ni < NREP; ++ni) {
            const long col = n0 + wcc * (BN / 4) + ni * 16 + l15;
            const float bcol = bias[(long)e * N + col];
#pragma unroll
            for (int r = 0; r < 4; ++r) {
                float v = acc[mi][ni][r] + bcol;
                if constexpr (EPI == 0) v = gelu_fast(v);
                Hout[(grow0 + r) * N + col] = f2bf(v);
            }
        }
    }
#undef RD_A
#undef RD_B
#undef MMA_Q
#undef VMC
}

// ------------------------------------------------------------- combine
// out[t][:] = w0 * Y[pos0][:] + w1 * Y[pos1][:]   (Y bf16, fp32 accumulate)
__global__ __launch_bounds__(256) void combine_kernel(const unsigned short* __restrict__ Y,
                                                      const int* __restrict__ posOf,
                                                      const float* __restrict__ tokW,
                                                      float* __restrict__ out) {
    const int t = blockIdx.x;
    const int p0 = posOf[t * 2];
    const int p1 = posOf[t * 2 + 1];
    const float w0 = tokW[t * 2];
    const float w1 = tokW[t * 2 + 1];
    const ushort4 a = ((const ushort4*)(Y + (long)p0 * HD))[threadIdx.x];
    const ushort4 b = ((const ushort4*)(Y + (long)p1 * HD))[threadIdx.x];
    float4 o;
    o.x = w0 * bf2f(a.x) + w1 * bf2f(b.x);
    o.y = w0 * bf2f(a.y) + w1 * bf2f(b.y);
    o.z = w0 * bf2f(a.z) + w1 * bf2f(b.z);
    o.w = w0 * bf2f(a.w) + w1 * bf2f(b.w);
    ((float4*)(out + (long)t * HD))[threadIdx.x] = o;
}

// ------------------------------------------------------------- launch
extern "C" void kernel_launch(void* const* d_in, const int* in_sizes, int n_in,
                              void* d_out, int out_size, void* d_ws, size_t ws_size,
                              hipStream_t stream) {
    const float* x  = (const float*)d_in[0];   // [4,2048,1024]
    const float* wr = (const float*)d_in[1];   // [8,1024]
    const float* w1 = (const float*)d_in[2];   // [8,4096,1024]
    const float* b1 = (const float*)d_in[3];   // [8,4096]
    const float* w2 = (const float*)d_in[4];   // [8,1024,4096]
    const float* b2 = (const float*)d_in[5];   // [8,1024]
    float* out = (float*)d_out;                // [4,2048,1024] fp32

    const size_t WBYTES = (size_t)NE * DFF * HD * 2;  // 67.1 MB per weight
    const bool full = ws_size >= (size_t)326 * 1024 * 1024;

    char* p = (char*)d_ws;
    auto alloc = [&](size_t bytes) {
        char* r = p;
        p += (bytes + 255) & ~(size_t)255;
        return r;
    };
    unsigned short* Xg  = (unsigned short*)alloc((size_t)ROWCAP * HD * 2);   // 37.7 MB
    unsigned short* H1g = (unsigned short*)alloc((size_t)ROWCAP * DFF * 2);  // 151 MB
    unsigned short* Wb1 = (unsigned short*)alloc(WBYTES);                    // 67.1 MB
    unsigned short* Wb2 = full ? (unsigned short*)alloc(WBYTES) : Wb1;
    int*   rowTok  = (int*)alloc((size_t)ROWCAP * 4);
    int*   posOf   = (int*)alloc((size_t)TT * 2 * 4);
    int*   tokE    = (int*)alloc((size_t)TT * 2 * 4);
    float* tokW    = (float*)alloc((size_t)TT * 2 * 4);
    int*   counts  = (int*)alloc(64);
    int*   cursor  = (int*)alloc(64);
    int*   tE      = (int*)alloc(MAXT * 4);
    int*   tR      = (int*)alloc(MAXT * 4);

    // Yg (FC2 per-row bf16 output) reuses the Xg slot (Xg dead after FC1).
    unsigned short* Yg = Xg;

    hipMemsetAsync(counts, 0, 64, stream);

    const long n4w = (long)NE * DFF * HD / 4;
    if (full) {
        cvt_w2_kernel<<<dim3(8192), dim3(256), 0, stream>>>(w1, Wb1, w2, Wb2, n4w);
    } else {
        cvt_w_kernel<<<dim3(4096), dim3(256), 0, stream>>>(w1, Wb1, n4w);
    }

    router_kernel<<<dim3(TT / 4), dim3(256), 0, stream>>>(x, wr, tokE, tokW, counts);
    init_setup_kernel<<<dim3(ROWCAP / 256 + 1), dim3(256), 0, stream>>>(
        counts, cursor, tE, tR, rowTok);
    scatter_kernel<<<dim3(TT / 256), dim3(256), 0, stream>>>(tokE, cursor, rowTok, posOf);
    gather_kernel<<<dim3(ROWCAP), dim3(256), 0, stream>>>(x, rowTok, Xg);

    // FC1: H1g = gelu(Xg @ w1[e]^T + b1[e]);  256x256 tiles, grid 72x16
    gemm4p<0, DFF, HD, 256><<<dim3(MAXT, DFF / 256), dim3(512), 0, stream>>>(
        Xg, Wb1, tE, tR, H1g, b1);

    // FC2: Yg = H1g @ w2[e]^T + b2[e];  256x128 tiles, grid 72x8
    if (!full)
        cvt_w_kernel<<<dim3(4096), dim3(256), 0, stream>>>(w2, Wb1, n4w);
    gemm4p<1, HD, DFF, 128><<<dim3(MAXT, HD / 128), dim3(512), 0, stream>>>(
        H1g, Wb2, tE, tR, Yg, b2);

    // combine: out[t] = w0 * Yg[pos0(t)] + w1 * Yg[pos1(t)]
    combine_kernel<<<dim3(TT), dim3(256), 0, stream>>>(Yg, posOf, tokW, out);
}